// Round 1
// baseline (15045.065 us; speedup 1.0000x reference)
//
#include <hip/hip_runtime.h>
#include <math.h>

#define NDIMX 2941
#define NQ 1200
#define KB 800
#define KP 720
#define KU 1520
#define NC 400
#define NBATCH 128
#define NRHS 528

// ---------------- Gram kernel (f32 accumulate, f64 store) ----------------
__device__ __forceinline__ const float* qrowp(int rr, const float* Yf, const float* Uf,
                                              const float* Up, const float* Yp){
  if (rr < 480) return Yf + (size_t)rr*NDIMX;
  if (rr < 800) return Uf + (size_t)(rr-480)*NDIMX;
  if (rr < 960) return Up + (size_t)(rr-800)*NDIMX;
  return Yp + (size_t)(rr-960)*NDIMX;
}

__global__ __launch_bounds__(256) void k_gram(const float* __restrict__ Yf, const float* __restrict__ Uf,
    const float* __restrict__ Up, const float* __restrict__ Yp, double* __restrict__ G){
  int rem = blockIdx.x, ti = 0;
  while (rem >= ti+1){ rem -= ti+1; ++ti; }
  int tj = rem;
  __shared__ float At[32][37];
  __shared__ float Bt[32][37];
  int tid = threadIdx.x, tx = tid%16, ty = tid/16;
  float acc00=0.f, acc01=0.f, acc10=0.f, acc11=0.f;
  int i0 = ti*32, j0 = tj*32;
  for (int k0 = 0; k0 < NDIMX; k0 += 32){
    for (int l = tid; l < 1024; l += 256){
      int r2 = l >> 5, k = l & 31;
      int gr = i0 + r2, gk = k0 + k;
      At[r2][k] = (gr < NQ && gk < NDIMX) ? qrowp(gr,Yf,Uf,Up,Yp)[gk] : 0.f;
    }
    if (ti != tj){
      for (int l = tid; l < 1024; l += 256){
        int r2 = l >> 5, k = l & 31;
        int gr = j0 + r2, gk = k0 + k;
        Bt[r2][k] = (gr < NQ && gk < NDIMX) ? qrowp(gr,Yf,Uf,Up,Yp)[gk] : 0.f;
      }
    }
    __syncthreads();
    float (*Bp)[37] = (ti==tj) ? At : Bt;
    #pragma unroll
    for (int kk=0; kk<32; ++kk){
      float a0 = At[ty*2][kk], a1 = At[ty*2+1][kk];
      float b0 = Bp[tx*2][kk], b1 = Bp[tx*2+1][kk];
      acc00 += a0*b0; acc01 += a0*b1; acc10 += a1*b0; acc11 += a1*b1;
    }
    __syncthreads();
  }
  int gi0 = i0 + ty*2, gj0 = j0 + tx*2;
  if (gi0 < NQ && gj0 < NQ){ double v = acc00; G[(size_t)gi0*NQ+gj0]=v; G[(size_t)gj0*NQ+gi0]=v; }
  if (gi0 < NQ && gj0+1 < NQ){ double v = acc01; G[(size_t)gi0*NQ+gj0+1]=v; G[(size_t)(gj0+1)*NQ+gi0]=v; }
  if (gi0+1 < NQ && gj0 < NQ){ double v = acc10; G[(size_t)(gi0+1)*NQ+gj0]=v; G[(size_t)gj0*NQ+gi0+1]=v; }
  if (gi0+1 < NQ && gj0+1 < NQ){ double v = acc11; G[(size_t)(gi0+1)*NQ+gj0+1]=v; G[(size_t)(gj0+1)*NQ+gi0+1]=v; }
}

// ---------------- small helper kernels ----------------
__global__ void k_consts(const float* __restrict__ lam, double* __restrict__ c){
  if (threadIdx.x==0 && blockIdx.x==0){
    double sg = 2.0*(double)lam[0];
    c[0]=1.0; c[1]=0.0; c[2]=-1.0; c[3]=sg;
    c[4]=1.0/sg; c[5]=-1.0/sg; c[6]=1.0/(sg*sg); c[7]=-1.0/(sg*sg);
  }
}

__global__ __launch_bounds__(256) void k_asm_M11(const double* __restrict__ G, const float* __restrict__ q,
    const float* __restrict__ r, const double* __restrict__ cst, double* __restrict__ M11){
  int idx = blockIdx.x*256 + threadIdx.x;
  if (idx >= KB*KB) return;
  int i = idx / KB, j = idx % KB;
  double v = G[(size_t)i*NQ + j]*cst[4];
  if (i == j){
    double w = (i<480) ? (double)q[i%12] : (double)r[(i-480)%8];
    v += 0.5/w;
  }
  M11[idx] = v;
}

__global__ __launch_bounds__(256) void k_asm_M12(const double* __restrict__ G, const double* __restrict__ cst,
    double* __restrict__ M12){
  int idx = blockIdx.x*256 + threadIdx.x;
  if (idx >= KB*KP) return;
  int i = idx / KP, j = idx % KP;
  int pc = (j < 400) ? (800 + j) : (80 + j);
  M12[idx] = G[(size_t)i*NQ + pc]*cst[4];
}

__global__ __launch_bounds__(256) void k_asm_J(const double* __restrict__ G, double* __restrict__ J,
    double* __restrict__ R1){
  int idx = blockIdx.x*256 + threadIdx.x;
  if (idx >= KU*NC) return;
  int i = idx / NC, j = idx % NC;
  int ur = (i < 1200) ? i : (i - 720);
  double v = G[(size_t)ur*NQ + 800 + j];
  J[(size_t)i*NC + j] = v;
  R1[(size_t)i*NRHS + j] = v;
}

__global__ __launch_bounds__(256) void k_asm_GUB(const double* __restrict__ G, double* __restrict__ GUB){
  int idx = blockIdx.x*256 + threadIdx.x;
  if (idx >= KU*KB) return;
  int i = idx / KB, k = idx % KB;
  int ur = (i < 1200) ? i : (i - 720);
  GUB[idx] = G[(size_t)ur*NQ + k];
}

__global__ __launch_bounds__(256) void k_build_d(const float* __restrict__ q, const float* __restrict__ r,
    const float* __restrict__ yref, const float* __restrict__ uref, double* __restrict__ dM){
  int idx = blockIdx.x*256 + threadIdx.x;
  if (idx >= KB*NBATCH) return;
  int k = idx / NBATCH, t = idx % NBATCH;
  double v;
  if (k < 480) v = 2.0*(double)q[k%12]*(double)yref[(size_t)t*480 + k];
  else         v = 2.0*(double)r[(k-480)%8]*(double)uref[(size_t)t*320 + (k-480)];
  dM[idx] = v;
}

__global__ __launch_bounds__(256) void k_build_negb(const float* __restrict__ u_ini,
    const float* __restrict__ y_ini, double* __restrict__ nb){
  int idx = blockIdx.x*256 + threadIdx.x;
  if (idx >= NC*NBATCH) return;
  int j = idx / NBATCH, t = idx % NBATCH;
  double v = (j < 160) ? (double)u_ini[(size_t)t*160 + j] : (double)y_ini[(size_t)t*240 + (j-160)];
  nb[idx] = -v;
}

__global__ __launch_bounds__(256) void k_out(const double* __restrict__ Bg, float* __restrict__ out){
  int idx = blockIdx.x*256 + threadIdx.x;
  if (idx < 128*320){
    int t = idx/320, i = idx%320;
    out[idx] = (float)Bg[(size_t)(480+i)*NBATCH + t];
  } else if (idx < 128*320 + 128*480){
    int l = idx - 128*320;
    int t = l/480, i = l%480;
    out[idx] = (float)Bg[(size_t)i*NBATCH + t];
  }
}

// ---------------- generic f64 GEMM: Cout = alpha*op(A)@B + beta*Cin ----------------
template<int TRANSA>
__global__ __launch_bounds__(256) void k_gemm(const double* __restrict__ A, int lda,
    const double* __restrict__ B, int ldb, const double* __restrict__ Cin, int ldcin,
    double* __restrict__ Cout, int ldc, int M, int N, int K,
    const double* __restrict__ alphaP, const double* __restrict__ betaP){
  __shared__ double As[16][66];
  __shared__ double Bs[16][66];
  int tid = threadIdx.x, tx = tid%16, ty = tid/16;
  int m0 = blockIdx.y*64, n0 = blockIdx.x*64;
  double acc[4][4] = {};
  for (int k0 = 0; k0 < K; k0 += 16){
    if (TRANSA == 0){
      for (int l = tid; l < 1024; l += 256){
        int m = l/16, k = l%16;
        int gm = m0+m, gk = k0+k;
        As[k][m] = (gm<M && gk<K) ? A[(size_t)gm*lda + gk] : 0.0;
      }
    } else {
      for (int l = tid; l < 1024; l += 256){
        int k = l/64, m = l%64;
        int gm = m0+m, gk = k0+k;
        As[k][m] = (gm<M && gk<K) ? A[(size_t)gk*lda + gm] : 0.0;
      }
    }
    for (int l = tid; l < 1024; l += 256){
      int k = l/64, n = l%64;
      int gn = n0+n, gk = k0+k;
      Bs[k][n] = (gn<N && gk<K) ? B[(size_t)gk*ldb + gn] : 0.0;
    }
    __syncthreads();
    #pragma unroll
    for (int kk=0; kk<16; ++kk){
      double a0=As[kk][ty*4+0], a1=As[kk][ty*4+1], a2=As[kk][ty*4+2], a3=As[kk][ty*4+3];
      double b0=Bs[kk][tx*4+0], b1=Bs[kk][tx*4+1], b2=Bs[kk][tx*4+2], b3=Bs[kk][tx*4+3];
      acc[0][0]+=a0*b0; acc[0][1]+=a0*b1; acc[0][2]+=a0*b2; acc[0][3]+=a0*b3;
      acc[1][0]+=a1*b0; acc[1][1]+=a1*b1; acc[1][2]+=a1*b2; acc[1][3]+=a1*b3;
      acc[2][0]+=a2*b0; acc[2][1]+=a2*b1; acc[2][2]+=a2*b2; acc[2][3]+=a2*b3;
      acc[3][0]+=a3*b0; acc[3][1]+=a3*b1; acc[3][2]+=a3*b2; acc[3][3]+=a3*b3;
    }
    __syncthreads();
  }
  double alpha = *alphaP, beta = *betaP;
  for (int i=0;i<4;i++) for (int j=0;j<4;j++){
    int gm = m0 + ty*4 + i, gn = n0 + tx*4 + j;
    if (gm < M && gn < N){
      double v = alpha*acc[i][j];
      if (beta != 0.0) v += beta*Cin[(size_t)gm*ldcin + gn];
      Cout[(size_t)gm*ldc + gn] = v;
    }
  }
}

// ---------------- blocked Cholesky (lower, in-place, NB=64) ----------------
__global__ __launch_bounds__(256) void k_potf2(double* __restrict__ A, int lda, int n, int j0){
  int bs = n - j0; if (bs > 64) bs = 64;
  __shared__ double sm[64][65];
  int tid = threadIdx.x;
  for (int l = tid; l < bs*bs; l += 256){ int i=l/bs, j=l%bs; sm[i][j] = A[(size_t)(j0+i)*lda + j0+j]; }
  __syncthreads();
  for (int j=0;j<bs;j++){
    if (tid==0) sm[j][j] = sqrt(sm[j][j]);
    __syncthreads();
    double dinv = 1.0/sm[j][j];
    for (int i=j+1+tid; i<bs; i+=256) sm[i][j] *= dinv;
    __syncthreads();
    int tx=tid%16, ty=tid/16;
    for (int i=j+1+ty; i<bs; i+=16)
      for (int k=j+1+tx; k<=i; k+=16)
        sm[i][k] -= sm[i][j]*sm[k][j];
    __syncthreads();
  }
  for (int l = tid; l < bs*bs; l += 256){ int i=l/bs, j=l%bs; A[(size_t)(j0+i)*lda + j0+j] = sm[i][j]; }
}

__global__ __launch_bounds__(256) void k_trsm_panel(double* __restrict__ A, int lda, int n, int j0){
  __shared__ double ldp[2080];
  __shared__ double X[64][65];
  int tid = threadIdx.x;
  int r0 = j0 + 64 + blockIdx.x*64;
  int nr = n - r0; if (nr > 64) nr = 64;
  for (int i=0;i<64;i++)
    for (int j=tid; j<=i; j+=256)
      ldp[i*(i+1)/2 + j] = A[(size_t)(j0+i)*lda + j0+j];
  for (int l=tid; l<4096; l+=256){ int i=l/64, j=l%64; X[i][j] = (i<nr) ? A[(size_t)(r0+i)*lda + j0+j] : 0.0; }
  __syncthreads();
  int i = tid & 63, ty = tid >> 6;
  for (int j=0;j<64;j++){
    if (ty==0) X[i][j] /= ldp[j*(j+1)/2 + j];
    __syncthreads();
    for (int k=j+1+ty; k<64; k+=4) X[i][k] -= X[i][j]*ldp[k*(k+1)/2 + j];
    __syncthreads();
  }
  for (int l=tid; l<4096; l+=256){ int i2=l/64, j2=l%64; if (i2<nr) A[(size_t)(r0+i2)*lda + j0+j2] = X[i2][j2]; }
}

__global__ __launch_bounds__(256) void k_syrk(double* __restrict__ A, int lda, int n, int j0){
  int rem = blockIdx.x, ti=0;
  while (rem >= ti+1){ rem -= ti+1; ++ti; }
  int tj = rem;
  int base = j0 + 64;
  int i0 = base + ti*64, jj0 = base + tj*64;
  int ni = n - i0; if (ni > 64) ni = 64;
  int nj = n - jj0; if (nj > 64) nj = 64;
  __shared__ double Ai[64][33];
  __shared__ double Aj[64][33];
  int tid = threadIdx.x, tx = tid%16, ty = tid/16;
  double acc[4][4] = {};
  for (int k0=0; k0<64; k0+=32){
    for (int l=tid; l<2048; l+=256){ int r2=l/32, k=l%32; Ai[r2][k] = (r2<ni) ? A[(size_t)(i0+r2)*lda + j0+k0+k] : 0.0; }
    if (ti != tj){
      for (int l=tid; l<2048; l+=256){ int r2=l/32, k=l%32; Aj[r2][k] = (r2<nj) ? A[(size_t)(jj0+r2)*lda + j0+k0+k] : 0.0; }
    }
    __syncthreads();
    double (*Bj)[33] = (ti==tj) ? Ai : Aj;
    #pragma unroll 8
    for (int kk=0; kk<32; ++kk){
      double a0=Ai[ty*4+0][kk], a1=Ai[ty*4+1][kk], a2=Ai[ty*4+2][kk], a3=Ai[ty*4+3][kk];
      double b0=Bj[tx*4+0][kk], b1=Bj[tx*4+1][kk], b2=Bj[tx*4+2][kk], b3=Bj[tx*4+3][kk];
      acc[0][0]+=a0*b0; acc[0][1]+=a0*b1; acc[0][2]+=a0*b2; acc[0][3]+=a0*b3;
      acc[1][0]+=a1*b0; acc[1][1]+=a1*b1; acc[1][2]+=a1*b2; acc[1][3]+=a1*b3;
      acc[2][0]+=a2*b0; acc[2][1]+=a2*b1; acc[2][2]+=a2*b2; acc[2][3]+=a2*b3;
      acc[3][0]+=a3*b0; acc[3][1]+=a3*b1; acc[3][2]+=a3*b2; acc[3][3]+=a3*b3;
    }
    __syncthreads();
  }
  for (int i2=0;i2<4;i2++) for (int j2=0;j2<4;j2++){
    int li = ty*4+i2, lj = tx*4+j2;
    if (li < ni && lj < nj){
      size_t off = (size_t)(i0+li)*lda + jj0+lj;
      A[off] -= acc[i2][j2];
    }
  }
}

// ---------------- blocked triangular solves (NB=64), X in-place ----------------
__global__ __launch_bounds__(256) void k_fwd_block(const double* __restrict__ L, int ldl, int n, int i0,
    double* __restrict__ X, int ldx, int ncols){
  int bs = n - i0; if (bs > 64) bs = 64;
  int c0 = blockIdx.x*64;
  int tid = threadIdx.x, tx = tid%16, ty = tid/16;
  __shared__ double Ls[16][66];
  __shared__ double Bs[16][66];
  __shared__ double ldp[2080];
  __shared__ double rowj[64];
  double acc[4][4] = {};
  for (int k0=0; k0<i0; k0+=16){
    for (int l=tid; l<1024; l+=256){
      int r2 = l/16, k = l%16;
      Ls[k][r2] = (r2<bs) ? L[(size_t)(i0+r2)*ldl + k0+k] : 0.0;
    }
    for (int l=tid; l<1024; l+=256){
      int k = l/64, c = l%64;
      Bs[k][c] = (c0+c < ncols) ? X[(size_t)(k0+k)*ldx + c0+c] : 0.0;
    }
    __syncthreads();
    #pragma unroll
    for (int kk=0; kk<16; ++kk){
      double a0=Ls[kk][ty*4+0], a1=Ls[kk][ty*4+1], a2=Ls[kk][ty*4+2], a3=Ls[kk][ty*4+3];
      double b0=Bs[kk][tx*4+0], b1=Bs[kk][tx*4+1], b2=Bs[kk][tx*4+2], b3=Bs[kk][tx*4+3];
      acc[0][0]+=a0*b0; acc[0][1]+=a0*b1; acc[0][2]+=a0*b2; acc[0][3]+=a0*b3;
      acc[1][0]+=a1*b0; acc[1][1]+=a1*b1; acc[1][2]+=a1*b2; acc[1][3]+=a1*b3;
      acc[2][0]+=a2*b0; acc[2][1]+=a2*b1; acc[2][2]+=a2*b2; acc[2][3]+=a2*b3;
      acc[3][0]+=a3*b0; acc[3][1]+=a3*b1; acc[3][2]+=a3*b2; acc[3][3]+=a3*b3;
    }
    __syncthreads();
  }
  for (int i=0;i<64;i++)
    for (int j=tid; j<=i; j+=256)
      ldp[i*(i+1)/2 + j] = (i<bs && j<bs) ? L[(size_t)(i0+i)*ldl + i0+j] : (i==j ? 1.0 : 0.0);
  __syncthreads();
  double rr[4][4];
  for (int i=0;i<4;i++) for (int j=0;j<4;j++){
    int gr = ty*4+i, gc = tx*4+j;
    rr[i][j] = (gr<bs && c0+gc<ncols) ? (X[(size_t)(i0+gr)*ldx + c0+gc] - acc[i][j]) : 0.0;
  }
  for (int j=0;j<bs;j++){
    double dj = ldp[j*(j+1)/2 + j];
    if (ty == (j>>2)){
      int jr = j & 3;
      #pragma unroll
      for (int c=0;c<4;c++){ double v = rr[jr][c]/dj; rr[jr][c]=v; rowj[tx*4+c]=v; }
    }
    __syncthreads();
    for (int i=0;i<4;i++){
      int gi = ty*4+i;
      if (gi > j){
        double lij = ldp[gi*(gi+1)/2 + j];
        #pragma unroll
        for (int c=0;c<4;c++) rr[i][c] -= lij*rowj[tx*4+c];
      }
    }
    __syncthreads();
  }
  for (int i=0;i<4;i++) for (int j=0;j<4;j++){
    int gr = ty*4+i, gc = tx*4+j;
    if (gr<bs && c0+gc<ncols) X[(size_t)(i0+gr)*ldx + c0+gc] = rr[i][j];
  }
}

__global__ __launch_bounds__(256) void k_bwd_block(const double* __restrict__ L, int ldl, int n, int i0,
    double* __restrict__ X, int ldx, int ncols){
  int bs = n - i0; if (bs > 64) bs = 64;
  int i1 = i0 + bs;
  int c0 = blockIdx.x*64;
  int tid = threadIdx.x, tx = tid%16, ty = tid/16;
  __shared__ double Ls[16][66];
  __shared__ double Bs[16][66];
  __shared__ double ldp[2080];
  __shared__ double rowj[64];
  double acc[4][4] = {};
  for (int k0=i1; k0<n; k0+=16){
    for (int l=tid; l<1024; l+=256){
      int k = l/64, r2 = l%64;
      int kg = k0+k;
      Ls[k][r2] = (kg<n && r2<bs) ? L[(size_t)kg*ldl + i0+r2] : 0.0;
    }
    for (int l=tid; l<1024; l+=256){
      int k = l/64, c = l%64;
      int kg = k0+k;
      Bs[k][c] = (kg<n && c0+c<ncols) ? X[(size_t)kg*ldx + c0+c] : 0.0;
    }
    __syncthreads();
    #pragma unroll
    for (int kk=0; kk<16; ++kk){
      double a0=Ls[kk][ty*4+0], a1=Ls[kk][ty*4+1], a2=Ls[kk][ty*4+2], a3=Ls[kk][ty*4+3];
      double b0=Bs[kk][tx*4+0], b1=Bs[kk][tx*4+1], b2=Bs[kk][tx*4+2], b3=Bs[kk][tx*4+3];
      acc[0][0]+=a0*b0; acc[0][1]+=a0*b1; acc[0][2]+=a0*b2; acc[0][3]+=a0*b3;
      acc[1][0]+=a1*b0; acc[1][1]+=a1*b1; acc[1][2]+=a1*b2; acc[1][3]+=a1*b3;
      acc[2][0]+=a2*b0; acc[2][1]+=a2*b1; acc[2][2]+=a2*b2; acc[2][3]+=a2*b3;
      acc[3][0]+=a3*b0; acc[3][1]+=a3*b1; acc[3][2]+=a3*b2; acc[3][3]+=a3*b3;
    }
    __syncthreads();
  }
  for (int i=0;i<64;i++)
    for (int j=tid; j<=i; j+=256)
      ldp[i*(i+1)/2 + j] = (i<bs && j<bs) ? L[(size_t)(i0+i)*ldl + i0+j] : (i==j ? 1.0 : 0.0);
  __syncthreads();
  double rr[4][4];
  for (int i=0;i<4;i++) for (int j=0;j<4;j++){
    int gr = ty*4+i, gc = tx*4+j;
    rr[i][j] = (gr<bs && c0+gc<ncols) ? (X[(size_t)(i0+gr)*ldx + c0+gc] - acc[i][j]) : 0.0;
  }
  for (int j=bs-1; j>=0; j--){
    double dj = ldp[j*(j+1)/2 + j];
    if (ty == (j>>2)){
      int jr = j & 3;
      #pragma unroll
      for (int c=0;c<4;c++){ double v = rr[jr][c]/dj; rr[jr][c]=v; rowj[tx*4+c]=v; }
    }
    __syncthreads();
    int rowbase = j*(j+1)/2;
    for (int i=0;i<4;i++){
      int gi = ty*4+i;
      if (gi < j){
        double lji = ldp[rowbase + gi];
        #pragma unroll
        for (int c=0;c<4;c++) rr[i][c] -= lji*rowj[tx*4+c];
      }
    }
    __syncthreads();
  }
  for (int i=0;i<4;i++) for (int j=0;j<4;j++){
    int gr = ty*4+i, gc = tx*4+j;
    if (gr<bs && c0+gc<ncols) X[(size_t)(i0+gr)*ldx + c0+gc] = rr[i][j];
  }
}

// ---------------- host drivers ----------------
static void gemm_l(hipStream_t s, int transA, const double* A, int lda, const double* B, int ldb,
                   const double* Cin, int ldcin, double* Cout, int ldc, int M, int N, int K,
                   const double* al, const double* be){
  dim3 g((N+63)/64, (M+63)/64);
  if (transA) k_gemm<1><<<g,256,0,s>>>(A,lda,B,ldb,Cin,ldcin,Cout,ldc,M,N,K,al,be);
  else        k_gemm<0><<<g,256,0,s>>>(A,lda,B,ldb,Cin,ldcin,Cout,ldc,M,N,K,al,be);
}

static void chol_l(hipStream_t s, double* A, int lda, int n){
  for (int j0=0; j0<n; j0+=64){
    int rem = n - j0;
    k_potf2<<<1,256,0,s>>>(A,lda,n,j0);
    if (rem > 64){
      int nb = (rem - 64 + 63)/64;
      k_trsm_panel<<<nb,256,0,s>>>(A,lda,n,j0);
      k_syrk<<<nb*(nb+1)/2,256,0,s>>>(A,lda,n,j0);
    }
  }
}

static void fwd_l(hipStream_t s, const double* L, int ldl, int n, double* X, int ldx, int ncols){
  int g = (ncols+63)/64;
  for (int i0=0; i0<n; i0+=64) k_fwd_block<<<g,256,0,s>>>(L,ldl,n,i0,X,ldx,ncols);
}

static void bwd_l(hipStream_t s, const double* L, int ldl, int n, double* X, int ldx, int ncols){
  int g = (ncols+63)/64;
  int last = ((n-1)/64)*64;
  for (int i0=last; i0>=0; i0-=64) k_bwd_block<<<g,256,0,s>>>(L,ldl,n,i0,X,ldx,ncols);
}

extern "C" void kernel_launch(void* const* d_in, const int* in_sizes, int n_in,
                              void* d_out, int out_size, void* d_ws, size_t ws_size,
                              hipStream_t stream){
  const float* Up   = (const float*)d_in[0];
  const float* Yp   = (const float*)d_in[1];
  const float* Uf   = (const float*)d_in[2];
  const float* Yf   = (const float*)d_in[3];
  // d_in[4] = IPI : intentionally unused (projector handled analytically)
  const float* q    = (const float*)d_in[5];
  const float* r    = (const float*)d_in[6];
  const float* lam  = (const float*)d_in[7];
  const float* yref = (const float*)d_in[8];
  const float* uref = (const float*)d_in[9];
  const float* u_ini= (const float*)d_in[10];
  const float* y_ini= (const float*)d_in[11];
  float* out = (float*)d_out;

  double* W = (double*)d_ws;
  size_t o = 0;
  double* Gram = W + o; o += (size_t)NQ*NQ;        // 1200x1200
  double* M11  = W + o; o += (size_t)KB*KB;        // 800x800 -> L1
  double* T12  = W + o; o += (size_t)KB*KP;        // 800x720 M12 -> T
  double* SP   = W + o; o += (size_t)KP*KP;        // 720x720 -> L2
  double* Jm   = W + o; o += (size_t)KU*NC;        // 1520x400
  double* GUB  = W + o; o += (size_t)KU*KB;        // 1520x800
  double* R1   = W + o; o += (size_t)KU*NRHS;      // 1520x528: [J | Ud] -> [Z | Zc]
  double* Sm   = W + o; o += (size_t)NC*NC;        // 400x400 -> chol
  double* dM   = W + o; o += (size_t)KB*NBATCH;    // 800x128
  double* rhs2 = W + o; o += (size_t)NC*NBATCH;    // 400x128 (-b -> nu)
  double* tAc  = W + o; o += (size_t)NC*NBATCH;    // 400x128
  double* P1   = W + o; o += (size_t)KB*NBATCH;    // 800x128 -> Bg
  double* BUZ  = W + o; o += (size_t)KB*NC;        // 800x400
  double* cst  = W + o; o += 16;
  if (ws_size < o*sizeof(double)) return;

  const double *C1 = &cst[0], *C0 = &cst[1], *Cm1 = &cst[2];
  const double *Cis = &cst[4], *Cmis = &cst[5], *Cis2 = &cst[6], *Cmis2 = &cst[7];

  k_consts<<<1,1,0,stream>>>(lam, cst);
  k_gram<<<741,256,0,stream>>>(Yf, Uf, Up, Yp, Gram);
  k_asm_M11<<<(KB*KB+255)/256,256,0,stream>>>(Gram, q, r, cst, M11);
  k_asm_M12<<<(KB*KP+255)/256,256,0,stream>>>(Gram, cst, T12);
  k_asm_J<<<(KU*NC+255)/256,256,0,stream>>>(Gram, Jm, R1);
  k_asm_GUB<<<(KU*KB+255)/256,256,0,stream>>>(Gram, GUB);
  k_build_d<<<(KB*NBATCH+255)/256,256,0,stream>>>(q, r, yref, uref, dM);
  k_build_negb<<<(NC*NBATCH+255)/256,256,0,stream>>>(u_ini, y_ini, rhs2);

  // Ud = GUB @ d  -> R1 cols 400..527
  gemm_l(stream, 0, GUB, KB, dM, NBATCH, R1+NC, NRHS, R1+NC, NRHS, KU, NBATCH, KB, C1, C0);

  // factor M11 = L1 L1^T ; T = L1^{-1} M12 ; S' = T^T T ; chol(S')
  chol_l(stream, M11, KB, KB);
  fwd_l(stream, M11, KB, KB, T12, KP, KP);
  gemm_l(stream, 1, T12, KP, T12, KP, SP, KP, SP, KP, KP, KP, KB, C1, C0);
  chol_l(stream, SP, KP, KP);

  // M^{-1} applied to R1 (528 cols), in place
  fwd_l(stream, M11, KB, KB, R1, NRHS, NRHS);                                  // w1' = L1^{-1} w1
  gemm_l(stream, 1, T12, KP, R1, NRHS, R1+(size_t)KB*NRHS, NRHS,
         R1+(size_t)KB*NRHS, NRHS, KP, NRHS, KB, C1, Cm1);                     // w2 := T^T w1' - w2
  fwd_l(stream, SP, KP, KP, R1+(size_t)KB*NRHS, NRHS, NRHS);
  bwd_l(stream, SP, KP, KP, R1+(size_t)KB*NRHS, NRHS, NRHS);                   // z2
  gemm_l(stream, 0, T12, KP, R1+(size_t)KB*NRHS, NRHS, R1, NRHS,
         R1, NRHS, KB, NRHS, KP, Cm1, C1);                                     // w1 := w1' - T z2
  bwd_l(stream, M11, KB, KB, R1, NRHS, NRHS);                                  // z1

  // S = (1/s) AA^T - (1/s^2) J^T Z ; chol(S)
  gemm_l(stream, 1, Jm, NC, R1, NRHS, Gram+(size_t)800*NQ+800, NQ,
         Sm, NC, NC, NC, KU, Cmis2, Cis);
  chol_l(stream, Sm, NC, NC);

  // rhs2 = (1/s) A B^T d - b - (1/s^2) J^T Zc ; nu = S^{-1} rhs2
  gemm_l(stream, 0, Gram+(size_t)800*NQ, NQ, dM, NBATCH, rhs2, NBATCH,
         tAc, NBATCH, NC, NBATCH, KB, Cis, C1);                                 // tAc = (1/s)Ac - b
  gemm_l(stream, 1, Jm, NC, R1+NC, NRHS, tAc, NBATCH,
         rhs2, NBATCH, NC, NBATCH, KU, Cmis2, C1);                              // rhs2
  fwd_l(stream, Sm, NC, NC, rhs2, NBATCH, NBATCH);
  bwd_l(stream, Sm, NC, NC, rhs2, NBATCH, NBATCH);                              // nu

  // Bg = (1/s)(BB^T d - BA^T nu) - (1/s^2)(BU Zc - BU Z nu)
  gemm_l(stream, 0, Gram, NQ, dM, NBATCH, P1, NBATCH, P1, NBATCH,
         KB, NBATCH, KB, Cis, C0);                                              // (1/s) BB^T d
  gemm_l(stream, 0, Gram+800, NQ, rhs2, NBATCH, P1, NBATCH, P1, NBATCH,
         KB, NBATCH, NC, Cmis, C1);                                             // -(1/s) BA^T nu
  gemm_l(stream, 1, GUB, KB, R1+NC, NRHS, P1, NBATCH, P1, NBATCH,
         KB, NBATCH, KU, Cmis2, C1);                                            // -(1/s^2) BU Zc
  gemm_l(stream, 1, GUB, KB, R1, NRHS, BUZ, NC, BUZ, NC,
         KB, NC, KU, C1, C0);                                                   // BUZ = BU Z
  gemm_l(stream, 0, BUZ, NC, rhs2, NBATCH, P1, NBATCH, P1, NBATCH,
         KB, NBATCH, NC, Cis2, C1);                                             // +(1/s^2) BUZ nu

  k_out<<<(102400+255)/256,256,0,stream>>>(P1, out);
}